// Round 4
// baseline (194.734 us; speedup 1.0000x reference)
//
#include <hip/hip_runtime.h>

#define IWE_H 480
#define IWE_W 640
#define IWE_HW (IWE_H * IWE_W)
#define FLOW_SCALING 128.0f
#define MAX_TS 1.0f

#define BAND_H 2
#define NBANDS (IWE_H / BAND_H)        // 240 bands of 2 rows
#define TROWS (BAND_H + 1)             // 2 owned rows + 1 halo row
#define CAP 8192                       // slots per (batch,band); ~2x uniform mean 4167
#define OVF_CAP 262144
#define SCAT_BLOCK 512
#define EV_PER_THREAD 8
#define CHUNK (SCAT_BLOCK * EV_PER_THREAD)   // 4096 events per block

static __device__ inline float4 nt_load4(const float4* p) {
    union { double d[2]; float4 v; } u;
    const double* q = (const double*)p;
    u.d[0] = __builtin_nontemporal_load(q);
    u.d[1] = __builtin_nontemporal_load(q + 1);
    return u.v;
}

// ---------------- pass 1: bin events into per-band record buckets ----------------
// record = {wy, wx with polarity in mantissa LSB} (8 B). LSB flip shifts wx by
// <=1 ulp(640) = 6.1e-5 px -> error far below threshold.
__global__ __launch_bounds__(SCAT_BLOCK, 1)
void ev_scatter(const float* __restrict__ ev, const float* __restrict__ flow,
                float2* __restrict__ recs, unsigned* __restrict__ cursors,
                unsigned* __restrict__ ovf_cnt, float4* __restrict__ ovf,
                int N)
{
    __shared__ unsigned s_cnt[NBANDS];
    __shared__ unsigned s_base[NBANDS];
    const int b = blockIdx.y;
    const int base_e = blockIdx.x * CHUNK;

    for (int i = threadIdx.x; i < NBANDS; i += SCAT_BLOCK) s_cnt[i] = 0;
    __syncthreads();

    int      bands[EV_PER_THREAD];
    unsigned ranks[EV_PER_THREAD];
    float    wys[EV_PER_THREAD], wxs[EV_PER_THREAD];

    const float* fb = flow + (size_t)b * 2 * IWE_HW;
    const float4* evb = reinterpret_cast<const float4*>(ev) + (size_t)b * N;

    #pragma unroll
    for (int i = 0; i < EV_PER_THREAD; ++i) {
        int e = base_e + i * SCAT_BLOCK + threadIdx.x;
        bands[i] = -1;
        if (e < N) {
            float4 ee = nt_load4(evb + e);                // NT: don't evict flow from L2
            float ts = ee.x, y = ee.y, x = ee.z, p = ee.w;
            int lin0 = (int)(y * (float)IWE_W + x);       // exact: < 2^24
            float fx = fb[lin0];
            float fy = fb[IWE_HW + lin0];
            float dt = (MAX_TS - ts) * FLOW_SCALING;
            float wy = y + dt * fy;
            float wx = x + dt * fx;
            int ity = (int)floorf(wy);
            int band = ity >> 1;                          // floor(ity/2), ok for negatives
            band = band < 0 ? 0 : (band >= NBANDS ? NBANDS - 1 : band);
            bands[i] = band;
            ranks[i] = atomicAdd(&s_cnt[band], 1u);       // LDS ds_add_rtn
            wys[i] = wy;
            unsigned bx = __float_as_uint(wx);
            bx = (bx & ~1u) | (p > 0.f ? 1u : 0u);        // LSB=1 -> positive polarity
            wxs[i] = __uint_as_float(bx);
        }
    }
    __syncthreads();
    for (int i = threadIdx.x; i < NBANDS; i += SCAT_BLOCK) {
        unsigned c = s_cnt[i];
        s_base[i] = c ? atomicAdd(&cursors[b * NBANDS + i], c) : 0u;
    }
    __syncthreads();
    #pragma unroll
    for (int i = 0; i < EV_PER_THREAD; ++i) {
        if (bands[i] < 0) continue;
        unsigned slot = s_base[bands[i]] + ranks[i];
        int bin = b * NBANDS + bands[i];
        if (slot < CAP) {
            recs[(size_t)bin * CAP + slot] = make_float2(wys[i], wxs[i]);
        } else {
            unsigned o = atomicAdd(ovf_cnt, 1u);
            if (o < OVF_CAP) ovf[o] = make_float4(wys[i], wxs[i], (float)blockIdx.y, 0.f);
        }
    }
}

// ---------------- pass 2: per-band LDS accumulation + store ----------------
__device__ inline void splat_rec(float2 rec, float* tile, int y0g)
{
    float wy = rec.x;
    unsigned bx = __float_as_uint(rec.y);
    int plane = (bx & 1u) ? 0 : 1;                        // pos=plane0, neg=plane1
    float wx = __uint_as_float(bx & ~1u);
    float ty = floorf(wy), lx = floorf(wx);
    float fy = wy - ty, fx = wx - lx;
    float w00 = (1.f - fy) * (1.f - fx);
    float w01 = (1.f - fy) * fx;
    float w10 = fy * (1.f - fx);
    float w11 = fy * fx;
    int ity = (int)ty, ilx = (int)lx;
    int rr = ity - y0g;
    float* pl = tile + plane * TROWS * IWE_W;
    bool xl = (unsigned)ilx       < IWE_W;
    bool xr = (unsigned)(ilx + 1) < IWE_W;
    if ((unsigned)ity < IWE_H && (unsigned)rr < TROWS) {
        if (xl) atomicAdd(&pl[rr * IWE_W + ilx],     w00);
        if (xr) atomicAdd(&pl[rr * IWE_W + ilx + 1], w01);
    }
    if ((unsigned)(ity + 1) < IWE_H && (unsigned)(rr + 1) < TROWS) {
        if (xl) atomicAdd(&pl[(rr + 1) * IWE_W + ilx],     w10);
        if (xr) atomicAdd(&pl[(rr + 1) * IWE_W + ilx + 1], w11);
    }
}

__global__ __launch_bounds__(512)
void band_splat(const float2* __restrict__ recs, const unsigned* __restrict__ cursors,
                float* __restrict__ out, float* __restrict__ halo)
{
    __shared__ float tile[2 * TROWS * IWE_W];             // 15 KB
    const int bg = blockIdx.x;                            // b*NBANDS + band
    const int band = bg % NBANDS;
    const int b = bg / NBANDS;
    const int y0g = band * BAND_H;

    for (int i = threadIdx.x; i < 2 * TROWS * IWE_W; i += 512) tile[i] = 0.f;
    __syncthreads();

    unsigned cnt = cursors[bg]; if (cnt > CAP) cnt = CAP;
    const float2* r = recs + (size_t)bg * CAP;

    unsigned i = threadIdx.x;
    for (; i + 3 * 512 < cnt; i += 4 * 512) {             // 4-deep load batching (ILP)
        float2 a0 = r[i], a1 = r[i + 512], a2 = r[i + 1024], a3 = r[i + 1536];
        splat_rec(a0, tile, y0g); splat_rec(a1, tile, y0g);
        splat_rec(a2, tile, y0g); splat_rec(a3, tile, y0g);
    }
    for (; i < cnt; i += 512) splat_rec(r[i], tile, y0g);
    __syncthreads();

    // owned rows 0..BAND_H-1: exclusive -> plain stores (no d_out memset needed)
    for (int j = threadIdx.x; j < 2 * BAND_H * IWE_W; j += 512) {
        int plane = j / (BAND_H * IWE_W);
        int rem   = j % (BAND_H * IWE_W);
        int rr = rem / IWE_W, x = rem % IWE_W;
        out[(((size_t)b * 2 + plane) * IWE_H + (y0g + rr)) * IWE_W + x] =
            tile[plane * TROWS * IWE_W + rr * IWE_W + x];
    }
    // halo row BAND_H -> halo buffer
    for (int j = threadIdx.x; j < 2 * IWE_W; j += 512) {
        int plane = j / IWE_W, x = j % IWE_W;
        halo[((size_t)bg * 2 + plane) * IWE_W + x] =
            tile[plane * TROWS * IWE_W + BAND_H * IWE_W + x];
    }
}

// ---------------- pass 3: add halo rows (unique targets, no atomics) ----------------
__global__ void halo_add(const float* __restrict__ halo, float* __restrict__ out, int B)
{
    int t = blockIdx.x * blockDim.x + threadIdx.x;
    int total = B * (NBANDS - 1) * 2 * IWE_W;
    if (t >= total) return;
    int x = t % IWE_W; int rest = t / IWE_W;
    int plane = rest & 1; rest >>= 1;
    int bi = rest % (NBANDS - 1);                          // band 0..NBANDS-2
    int b  = rest / (NBANDS - 1);
    int bg = b * NBANDS + bi;
    float v = halo[((size_t)bg * 2 + plane) * IWE_W + x];
    size_t oi = (((size_t)b * 2 + plane) * IWE_H + (size_t)(bi + 1) * BAND_H) * IWE_W + x;
    out[oi] += v;
}

// ---------------- pass 4: overflow fallback (expected empty) ----------------
__global__ void ovf_splat(const float4* __restrict__ ovf, const unsigned* __restrict__ ovf_cnt,
                          float* __restrict__ out)
{
    unsigned cnt = *ovf_cnt; if (cnt > OVF_CAP) cnt = OVF_CAP;
    for (unsigned i = blockIdx.x * blockDim.x + threadIdx.x; i < cnt;
         i += gridDim.x * blockDim.x) {
        float4 rec = ovf[i];
        float wy = rec.x;
        unsigned bx = __float_as_uint(rec.y);
        int plane = (bx & 1u) ? 0 : 1;
        float wx = __uint_as_float(bx & ~1u);
        int b = (int)rec.z;
        float ty = floorf(wy), lx = floorf(wx);
        float fy = wy - ty, fx = wx - lx;
        int ity = (int)ty, ilx = (int)lx;
        float* pl = out + ((size_t)b * 2 + plane) * IWE_HW;
        if ((unsigned)ity < IWE_H) {
            if ((unsigned)ilx       < IWE_W) atomicAdd(pl + ity * IWE_W + ilx,     (1.f-fy)*(1.f-fx));
            if ((unsigned)(ilx + 1) < IWE_W) atomicAdd(pl + ity * IWE_W + ilx + 1, (1.f-fy)*fx);
        }
        if ((unsigned)(ity + 1) < IWE_H) {
            if ((unsigned)ilx       < IWE_W) atomicAdd(pl + (ity+1) * IWE_W + ilx,     fy*(1.f-fx));
            if ((unsigned)(ilx + 1) < IWE_W) atomicAdd(pl + (ity+1) * IWE_W + ilx + 1, fy*fx);
        }
    }
}

// ---------------- fallback: direct atomic splat ----------------
__global__ void iwe_direct_kernel(const float* __restrict__ ev, const float* __restrict__ flow,
                                  float* __restrict__ out, int N)
{
    int n = blockIdx.x * blockDim.x + threadIdx.x;
    int b = blockIdx.y;
    if (n >= N) return;
    float4 e = *reinterpret_cast<const float4*>(ev + ((size_t)b * N + n) * 4);
    float ts = e.x, y = e.y, x = e.z, p = e.w;
    const float* fb = flow + (size_t)b * 2 * IWE_HW;
    int lin0 = (int)(y * (float)IWE_W + x);
    float fx = fb[lin0], fy = fb[IWE_HW + lin0];
    float dt = (MAX_TS - ts) * FLOW_SCALING;
    float wy = y + dt * fy, wx = x + dt * fx;
    float ty = floorf(wy), lx = floorf(wx);
    float fyf = wy - ty, fxf = wx - lx;
    int iy = (int)ty, ix = (int)lx;
    float* plane = out + ((size_t)b * 2 + (p > 0.f ? 0 : 1)) * IWE_HW;
    if ((unsigned)iy < IWE_H) {
        if ((unsigned)ix       < IWE_W) atomicAdd(plane + iy * IWE_W + ix,     (1.f-fyf)*(1.f-fxf));
        if ((unsigned)(ix + 1) < IWE_W) atomicAdd(plane + iy * IWE_W + ix + 1, (1.f-fyf)*fxf);
    }
    if ((unsigned)(iy + 1) < IWE_H) {
        if ((unsigned)ix       < IWE_W) atomicAdd(plane + (iy+1) * IWE_W + ix,     fyf*(1.f-fxf));
        if ((unsigned)(ix + 1) < IWE_W) atomicAdd(plane + (iy+1) * IWE_W + ix + 1, fyf*fxf);
    }
}

extern "C" void kernel_launch(void* const* d_in, const int* in_sizes, int n_in,
                              void* d_out, int out_size, void* d_ws, size_t ws_size,
                              hipStream_t stream) {
    const float* ev   = (const float*)d_in[0];   // [B,N,4]
    const float* flow = (const float*)d_in[1];   // [B,2,H,W]
    float* out = (float*)d_out;                  // [B,2,H,W]

    int B = in_sizes[1] / (2 * IWE_HW);
    int N = in_sizes[0] / (4 * B);

    // workspace layout
    size_t off_cursors = 0;                                   // B*240 u32 (<=8KB)
    size_t off_ovfcnt  = 8192;                                // 1 u32
    size_t off_halo    = 12288;                               // B*240*2*640 f32
    size_t halo_bytes  = (size_t)B * NBANDS * 2 * IWE_W * 4;
    size_t off_recs    = (off_halo + halo_bytes + 255) & ~(size_t)255;
    size_t recs_bytes  = (size_t)B * NBANDS * CAP * 8;
    size_t off_ovf     = off_recs + recs_bytes;
    size_t need        = off_ovf + (size_t)OVF_CAP * 16;

    if ((size_t)B * NBANDS * 4 > 8192 || need > ws_size) {
        hipMemsetAsync(d_out, 0, (size_t)out_size * sizeof(float), stream);
        dim3 grid((N + 255) / 256, B);
        iwe_direct_kernel<<<grid, dim3(256), 0, stream>>>(ev, flow, out, N);
        return;
    }

    char* ws = (char*)d_ws;
    unsigned* cursors = (unsigned*)(ws + off_cursors);
    unsigned* ovf_cnt = (unsigned*)(ws + off_ovfcnt);
    float*    halo    = (float*)(ws + off_halo);
    float2*   recs    = (float2*)(ws + off_recs);
    float4*   ovf     = (float4*)(ws + off_ovf);

    hipMemsetAsync(d_ws, 0, 12288, stream);                   // cursors + ovf_cnt

    dim3 sgrid((N + CHUNK - 1) / CHUNK, B);
    ev_scatter<<<sgrid, dim3(SCAT_BLOCK), 0, stream>>>(ev, flow, recs, cursors, ovf_cnt, ovf, N);

    band_splat<<<dim3(B * NBANDS), dim3(512), 0, stream>>>(recs, cursors, out, halo);

    int htotal = B * (NBANDS - 1) * 2 * IWE_W;
    halo_add<<<dim3((htotal + 255) / 256), dim3(256), 0, stream>>>(halo, out, B);

    ovf_splat<<<dim3(64), dim3(256), 0, stream>>>(ovf, ovf_cnt, out);
}

// Round 5
// 81.861 us; speedup vs baseline: 2.3788x; 2.3788x over previous
//
#include <hip/hip_runtime.h>

#define IWE_H 480
#define IWE_W 640
#define IWE_HW (IWE_H * IWE_W)
#define FLOW_SCALING 128.0f
#define MAX_TS 1.0f

#define BAND_H 2
#define NBANDS (IWE_H / BAND_H)        // 240 bands of 2 rows
#define CAP 8192                       // slots per (batch,band); ~2x uniform mean 4167
#define OVF_CAP 262144
#define SCAT_BLOCK 512
#define EV_PER_THREAD 16
#define CHUNK (SCAT_BLOCK * EV_PER_THREAD)   // 8192 events per block
#define FIXS 65536.0f

static __device__ inline float4 nt_load4(const float4* p) {
    union { double d[2]; float4 v; } u;
    const double* q = (const double*)p;
    u.d[0] = __builtin_nontemporal_load(q);
    u.d[1] = __builtin_nontemporal_load(q + 1);
    return u.v;
}

// ---------------- pass 0: pack flow into float2 (one gather per event later) ----
__global__ void flow_pack(const float* __restrict__ flow, float2* __restrict__ flowp,
                          int total)   // total = B*HW
{
    int i = blockIdx.x * blockDim.x + threadIdx.x;
    if (i >= total) return;
    int b = i / IWE_HW, lin = i % IWE_HW;
    const float* fb = flow + (size_t)b * 2 * IWE_HW;
    flowp[i] = make_float2(fb[lin], fb[IWE_HW + lin]);    // (fx, fy)
}

// ---------------- pass 1: bin events into per-band record buckets ----------------
// record = {wy, wx with polarity in mantissa LSB} (8 B). LSB flip shifts wx by
// <=1 ulp(640) = 6.1e-5 px -> error far below threshold.
__global__ __launch_bounds__(SCAT_BLOCK, 1)
void ev_scatter(const float* __restrict__ ev, const float2* __restrict__ flowp,
                float2* __restrict__ recs, unsigned* __restrict__ cursors,
                unsigned* __restrict__ ovf_cnt, float4* __restrict__ ovf,
                int N, int C, int lpb)   // C = chunks/batch; lpb = XCD lanes/batch (0 => 2D grid)
{
    __shared__ unsigned s_cnt[NBANDS];
    __shared__ unsigned s_base[NBANDS];

    int b, chunk;
    if (lpb) {                                    // XCD-pinned: blockIdx.x&7 ~ XCD
        int lane = blockIdx.x & 7;
        b = lane / lpb;                           // each XCD serves exactly one batch
        chunk = ((int)(blockIdx.x >> 3)) * lpb + (lane % lpb);
    } else { b = blockIdx.y; chunk = blockIdx.x; }
    const int base_e = chunk * CHUNK;             // may exceed N -> idle block

    for (int i = threadIdx.x; i < NBANDS; i += SCAT_BLOCK) s_cnt[i] = 0;
    __syncthreads();

    int      bands[EV_PER_THREAD];
    unsigned ranks[EV_PER_THREAD];
    float    wys[EV_PER_THREAD], wxs[EV_PER_THREAD];

    const float2* fb = flowp + (size_t)b * IWE_HW;
    const float4* evb = reinterpret_cast<const float4*>(ev) + (size_t)b * N;

    #pragma unroll
    for (int i = 0; i < EV_PER_THREAD; ++i) {
        int e = base_e + i * SCAT_BLOCK + threadIdx.x;
        bands[i] = -1;
        if (e < N && chunk < C) {
            float4 ee = nt_load4(evb + e);        // NT: don't evict flow from L2
            float ts = ee.x, y = ee.y, x = ee.z, p = ee.w;
            int lin0 = (int)(y * (float)IWE_W + x);   // exact: < 2^24
            float2 f = fb[lin0];
            float dt = (MAX_TS - ts) * FLOW_SCALING;
            float wy = y + dt * f.y;
            float wx = x + dt * f.x;
            int ity = (int)floorf(wy);
            int band = ity >> 1;                  // floor(ity/2), ok for negatives
            band = band < 0 ? 0 : (band >= NBANDS ? NBANDS - 1 : band);
            bands[i] = band;
            ranks[i] = atomicAdd(&s_cnt[band], 1u);
            wys[i] = wy;
            unsigned bx = __float_as_uint(wx);
            bx = (bx & ~1u) | (p > 0.f ? 1u : 0u);    // LSB=1 -> positive polarity
            wxs[i] = __uint_as_float(bx);
        }
    }
    __syncthreads();
    for (int i = threadIdx.x; i < NBANDS; i += SCAT_BLOCK) {
        unsigned c = s_cnt[i];
        s_base[i] = c ? atomicAdd(&cursors[b * NBANDS + i], c) : 0u;
    }
    __syncthreads();
    #pragma unroll
    for (int i = 0; i < EV_PER_THREAD; ++i) {
        if (bands[i] < 0) continue;
        unsigned slot = s_base[bands[i]] + ranks[i];
        int bin = b * NBANDS + bands[i];
        if (slot < CAP) {
            recs[(size_t)bin * CAP + slot] = make_float2(wys[i], wxs[i]);
        } else {
            unsigned o = atomicAdd(ovf_cnt, 1u);
            if (o < OVF_CAP) ovf[o] = make_float4(wys[i], wxs[i], (float)b, 0.f);
        }
    }
}

// ---------------- pass 2: per-band accumulation, NATIVE u64 fixed-point LDS atomics
// tile entry rr (rr=0..BAND_H-1) covers rows (y0g+rr, y0g+rr+1): lo32=row rr, hi32=row rr+1.
// Row r readout = lo[entry r] + hi[entry r-1]; halo row = hi[entry BAND_H-1].
__global__ __launch_bounds__(512)
void band_splat(const float2* __restrict__ recs, const unsigned* __restrict__ cursors,
                float* __restrict__ out, float* __restrict__ halo)
{
    __shared__ unsigned long long tile[2 * BAND_H * IWE_W];   // 20.5 KB
    const int bg = blockIdx.x;
    const int band = bg % NBANDS;
    const int b = bg / NBANDS;
    const int y0g = band * BAND_H;

    for (int i = threadIdx.x; i < 2 * BAND_H * IWE_W; i += 512) tile[i] = 0ull;
    __syncthreads();

    unsigned cnt = cursors[bg]; if (cnt > CAP) cnt = CAP;
    const float2* r = recs + (size_t)bg * CAP;

    for (unsigned i = threadIdx.x; i < cnt; i += 512) {
        float2 rec = r[i];
        float wy = rec.x;
        unsigned bx = __float_as_uint(rec.y);
        int plane = (bx & 1u) ? 0 : 1;            // pos=plane0, neg=plane1
        float wx = __uint_as_float(bx & ~1u);
        float ty = floorf(wy), lx = floorf(wx);
        float fy = wy - ty, fx = wx - lx;
        unsigned w00 = (unsigned)((1.f - fy) * (1.f - fx) * FIXS + 0.5f);
        unsigned w01 = (unsigned)((1.f - fy) * fx * FIXS + 0.5f);
        unsigned w10 = (unsigned)(fy * (1.f - fx) * FIXS + 0.5f);
        unsigned w11 = (unsigned)(fy * fx * FIXS + 0.5f);
        int ity = (int)ty, ilx = (int)lx;
        int rr = ity - y0g;
        unsigned long long vL, vR;
        int entry;
        if ((unsigned)rr < (unsigned)BAND_H) {    // ity in band (always < H)
            entry = rr;
            bool hiOK = (ity + 1) < IWE_H;        // top image row: mask halo half
            vL = (unsigned long long)w00 | ((unsigned long long)(hiOK ? w10 : 0u) << 32);
            vR = (unsigned long long)w01 | ((unsigned long long)(hiOK ? w11 : 0u) << 32);
        } else if (rr == -1) {                    // ity==-1 (clamped to band 0): row 0 only
            entry = 0;
            vL = w10; vR = w11;
        } else continue;                          // fully out of image
        unsigned long long* pl = tile + (plane * BAND_H + entry) * IWE_W;
        if ((unsigned)ilx       < IWE_W && vL) atomicAdd(&pl[ilx],     vL);
        if ((unsigned)(ilx + 1) < IWE_W && vR) atomicAdd(&pl[ilx + 1], vR);
    }
    __syncthreads();

    // owned rows: plain stores (no d_out memset needed anywhere)
    for (int j = threadIdx.x; j < 2 * BAND_H * IWE_W; j += 512) {
        int plane = j / (BAND_H * IWE_W);
        int rem   = j % (BAND_H * IWE_W);
        int rr = rem / IWE_W, x = rem % IWE_W;
        unsigned v = (unsigned)(tile[(plane * BAND_H + rr) * IWE_W + x] & 0xffffffffu);
        if (rr > 0) v += (unsigned)(tile[(plane * BAND_H + rr - 1) * IWE_W + x] >> 32);
        out[(((size_t)b * 2 + plane) * IWE_H + (y0g + rr)) * IWE_W + x] =
            (float)v * (1.f / FIXS);
    }
    // halo row y0g+BAND_H
    for (int j = threadIdx.x; j < 2 * IWE_W; j += 512) {
        int plane = j / IWE_W, x = j % IWE_W;
        unsigned v = (unsigned)(tile[(plane * BAND_H + BAND_H - 1) * IWE_W + x] >> 32);
        halo[((size_t)bg * 2 + plane) * IWE_W + x] = (float)v * (1.f / FIXS);
    }
}

// ---------------- pass 3: add halo rows (unique targets, no atomics) ----------------
__global__ void halo_add(const float* __restrict__ halo, float* __restrict__ out, int B)
{
    int t = blockIdx.x * blockDim.x + threadIdx.x;
    int total = B * (NBANDS - 1) * 2 * IWE_W;
    if (t >= total) return;
    int x = t % IWE_W; int rest = t / IWE_W;
    int plane = rest & 1; rest >>= 1;
    int bi = rest % (NBANDS - 1);
    int b  = rest / (NBANDS - 1);
    int bg = b * NBANDS + bi;
    float v = halo[((size_t)bg * 2 + plane) * IWE_W + x];
    size_t oi = (((size_t)b * 2 + plane) * IWE_H + (size_t)(bi + 1) * BAND_H) * IWE_W + x;
    out[oi] += v;
}

// ---------------- pass 4: overflow fallback (expected empty) ----------------
__global__ void ovf_splat(const float4* __restrict__ ovf, const unsigned* __restrict__ ovf_cnt,
                          float* __restrict__ out)
{
    unsigned cnt = *ovf_cnt; if (cnt > OVF_CAP) cnt = OVF_CAP;
    for (unsigned i = blockIdx.x * blockDim.x + threadIdx.x; i < cnt;
         i += gridDim.x * blockDim.x) {
        float4 rec = ovf[i];
        float wy = rec.x;
        unsigned bx = __float_as_uint(rec.y);
        int plane = (bx & 1u) ? 0 : 1;
        float wx = __uint_as_float(bx & ~1u);
        int b = (int)rec.z;
        float ty = floorf(wy), lx = floorf(wx);
        float fy = wy - ty, fx = wx - lx;
        int ity = (int)ty, ilx = (int)lx;
        float* pl = out + ((size_t)b * 2 + plane) * IWE_HW;
        if ((unsigned)ity < IWE_H) {
            if ((unsigned)ilx       < IWE_W) atomicAdd(pl + ity * IWE_W + ilx,     (1.f-fy)*(1.f-fx));
            if ((unsigned)(ilx + 1) < IWE_W) atomicAdd(pl + ity * IWE_W + ilx + 1, (1.f-fy)*fx);
        }
        if ((unsigned)(ity + 1) < IWE_H) {
            if ((unsigned)ilx       < IWE_W) atomicAdd(pl + (ity+1) * IWE_W + ilx,     fy*(1.f-fx));
            if ((unsigned)(ilx + 1) < IWE_W) atomicAdd(pl + (ity+1) * IWE_W + ilx + 1, fy*fx);
        }
    }
}

// ---------------- fallback: direct atomic splat ----------------
__global__ void iwe_direct_kernel(const float* __restrict__ ev, const float* __restrict__ flow,
                                  float* __restrict__ out, int N)
{
    int n = blockIdx.x * blockDim.x + threadIdx.x;
    int b = blockIdx.y;
    if (n >= N) return;
    float4 e = *reinterpret_cast<const float4*>(ev + ((size_t)b * N + n) * 4);
    float ts = e.x, y = e.y, x = e.z, p = e.w;
    const float* fb = flow + (size_t)b * 2 * IWE_HW;
    int lin0 = (int)(y * (float)IWE_W + x);
    float fx = fb[lin0], fy = fb[IWE_HW + lin0];
    float dt = (MAX_TS - ts) * FLOW_SCALING;
    float wy = y + dt * fy, wx = x + dt * fx;
    float ty = floorf(wy), lx = floorf(wx);
    float fyf = wy - ty, fxf = wx - lx;
    int iy = (int)ty, ix = (int)lx;
    float* plane = out + ((size_t)b * 2 + (p > 0.f ? 0 : 1)) * IWE_HW;
    if ((unsigned)iy < IWE_H) {
        if ((unsigned)ix       < IWE_W) atomicAdd(plane + iy * IWE_W + ix,     (1.f-fyf)*(1.f-fxf));
        if ((unsigned)(ix + 1) < IWE_W) atomicAdd(plane + iy * IWE_W + ix + 1, (1.f-fyf)*fxf);
    }
    if ((unsigned)(iy + 1) < IWE_H) {
        if ((unsigned)ix       < IWE_W) atomicAdd(plane + (iy+1) * IWE_W + ix,     fyf*(1.f-fxf));
        if ((unsigned)(ix + 1) < IWE_W) atomicAdd(plane + (iy+1) * IWE_W + ix + 1, fyf*fxf);
    }
}

extern "C" void kernel_launch(void* const* d_in, const int* in_sizes, int n_in,
                              void* d_out, int out_size, void* d_ws, size_t ws_size,
                              hipStream_t stream) {
    const float* ev   = (const float*)d_in[0];   // [B,N,4]
    const float* flow = (const float*)d_in[1];   // [B,2,H,W]
    float* out = (float*)d_out;                  // [B,2,H,W]

    int B = in_sizes[1] / (2 * IWE_HW);
    int N = in_sizes[0] / (4 * B);

    // workspace layout
    size_t off_cursors = 0;                                   // B*240 u32
    size_t off_ovfcnt  = 8192;
    size_t off_halo    = 12288;                               // B*240*2*640 f32
    size_t halo_bytes  = (size_t)B * NBANDS * 2 * IWE_W * 4;
    size_t off_flowp   = (off_halo + halo_bytes + 255) & ~(size_t)255;
    size_t flowp_bytes = (size_t)B * IWE_HW * 8;
    size_t off_recs    = (off_flowp + flowp_bytes + 255) & ~(size_t)255;
    size_t recs_bytes  = (size_t)B * NBANDS * CAP * 8;
    size_t off_ovf     = off_recs + recs_bytes;
    size_t need        = off_ovf + (size_t)OVF_CAP * 16;

    if ((size_t)B * NBANDS * 4 > 8192 || need > ws_size) {
        hipMemsetAsync(d_out, 0, (size_t)out_size * sizeof(float), stream);
        dim3 grid((N + 255) / 256, B);
        iwe_direct_kernel<<<grid, dim3(256), 0, stream>>>(ev, flow, out, N);
        return;
    }

    char* ws = (char*)d_ws;
    unsigned* cursors = (unsigned*)(ws + off_cursors);
    unsigned* ovf_cnt = (unsigned*)(ws + off_ovfcnt);
    float*    halo    = (float*)(ws + off_halo);
    float2*   flowp   = (float2*)(ws + off_flowp);
    float2*   recs    = (float2*)(ws + off_recs);
    float4*   ovf     = (float4*)(ws + off_ovf);

    hipMemsetAsync(d_ws, 0, 12288, stream);                   // cursors + ovf_cnt

    int ftotal = B * IWE_HW;
    flow_pack<<<dim3((ftotal + 255) / 256), dim3(256), 0, stream>>>(flow, flowp, ftotal);

    int C = (N + CHUNK - 1) / CHUNK;                          // chunks per batch
    if (B <= 8 && (8 % B) == 0) {
        int lpb = 8 / B;                                      // XCD lanes per batch
        int iters = (C + lpb - 1) / lpb;
        ev_scatter<<<dim3(8 * iters), dim3(SCAT_BLOCK), 0, stream>>>(
            ev, flowp, recs, cursors, ovf_cnt, ovf, N, C, lpb);
    } else {
        ev_scatter<<<dim3(C, B), dim3(SCAT_BLOCK), 0, stream>>>(
            ev, flowp, recs, cursors, ovf_cnt, ovf, N, C, 0);
    }

    band_splat<<<dim3(B * NBANDS), dim3(512), 0, stream>>>(recs, cursors, out, halo);

    int htotal = B * (NBANDS - 1) * 2 * IWE_W;
    halo_add<<<dim3((htotal + 255) / 256), dim3(256), 0, stream>>>(halo, out, B);

    ovf_splat<<<dim3(64), dim3(256), 0, stream>>>(ovf, ovf_cnt, out);
}

// Round 6
// 73.928 us; speedup vs baseline: 2.6341x; 1.1073x over previous
//
#include <hip/hip_runtime.h>

#define IWE_H 480
#define IWE_W 640
#define IWE_HW (IWE_H * IWE_W)
#define FLOW_SCALING 128.0f
#define MAX_TS 1.0f

#define BAND_H 2
#define NBANDS (IWE_H / BAND_H)        // 240 bands of 2 rows
#define CAP 8192                       // slots per (batch,band); ~2x uniform mean 4167
#define OVF_CAP 262144
#define SCAT_BLOCK 512
#define EV_PER_THREAD 8
#define CHUNK (SCAT_BLOCK * EV_PER_THREAD)   // 4096 events per block
#define QBITS 9
#define QMAX  512.0f                   // 2^QBITS
#define WSCALE (512.f * 512.f)         // weight fixed-point scale 2^18

static __device__ inline float4 nt_load4(const float4* p) {
    union { double d[2]; float4 v; } u;
    const double* q = (const double*)p;
    u.d[0] = __builtin_nontemporal_load(q);
    u.d[1] = __builtin_nontemporal_load(q + 1);
    return u.v;
}

// record (u32): [0:2) rr2  [2:12) xi+1  [12:21) qy  [21:30) qx  [30] pol
// rr2 = ity - 2*band + 1 in {0,1,2}; rr2==0 only for ity==-1 (band 0, row-0-only)

// ---------------- pass 0: pack flow to float2 + zero cursors/ovf_cnt ----------------
__global__ void flow_pack(const float* __restrict__ flow, float2* __restrict__ flowp,
                          unsigned* __restrict__ wszero, int total)
{
    int i = blockIdx.x * blockDim.x + threadIdx.x;
    if (i < 3072) wszero[i] = 0u;                         // cursors + ovf_cnt region
    if (i >= total) return;
    int b = i / IWE_HW, lin = i % IWE_HW;
    const float* fb = flow + (size_t)b * 2 * IWE_HW;
    flowp[i] = make_float2(fb[lin], fb[IWE_HW + lin]);    // (fx, fy)
}

// ---------------- pass 1: bin events into per-band u32 record buckets ----------------
__global__ __launch_bounds__(SCAT_BLOCK, 4)
void ev_scatter(const float* __restrict__ ev, const float2* __restrict__ flowp,
                unsigned* __restrict__ recs, unsigned* __restrict__ cursors,
                unsigned* __restrict__ ovf_cnt, float2* __restrict__ ovf,
                int N, int C, int lpb)   // lpb = XCD lanes/batch (0 => 2D grid)
{
    __shared__ unsigned s_cnt[NBANDS];
    __shared__ unsigned s_base[NBANDS];

    int b, chunk;
    if (lpb) {                                    // XCD-pinned: blockIdx.x&7 ~ XCD
        int lane = blockIdx.x & 7;
        b = lane / lpb;
        chunk = ((int)(blockIdx.x >> 3)) * lpb + (lane % lpb);
    } else { b = blockIdx.y; chunk = blockIdx.x; }
    const int base_e = chunk * CHUNK;
    const bool live_chunk = (chunk < C);

    for (int i = threadIdx.x; i < NBANDS; i += SCAT_BLOCK) s_cnt[i] = 0;
    __syncthreads();

    float4   ee[EV_PER_THREAD];
    float2   fl[EV_PER_THREAD];
    int      bands[EV_PER_THREAD];
    unsigned ranks[EV_PER_THREAD];
    unsigned recw[EV_PER_THREAD];

    const float2* fb = flowp + (size_t)b * IWE_HW;
    const float4* evb = reinterpret_cast<const float4*>(ev) + (size_t)b * N;

    // phase A: stream events (independent loads)
    #pragma unroll
    for (int i = 0; i < EV_PER_THREAD; ++i) {
        int e = base_e + i * SCAT_BLOCK + threadIdx.x;
        ee[i] = (live_chunk && e < N) ? nt_load4(evb + e)
                                      : make_float4(0.f, -1e9f, 0.f, 0.f);
    }
    // phase B: issue all flow gathers (8 in flight)
    #pragma unroll
    for (int i = 0; i < EV_PER_THREAD; ++i) {
        int lin0 = (int)(ee[i].y * (float)IWE_W + ee[i].z);   // exact: < 2^24
        fl[i] = (ee[i].y >= 0.f) ? fb[lin0] : make_float2(0.f, 0.f);
    }
    // phase C: warp, quantize, rank
    #pragma unroll
    for (int i = 0; i < EV_PER_THREAD; ++i) {
        bands[i] = -1;
        if (ee[i].y < 0.f) continue;
        float dt = (MAX_TS - ee[i].x) * FLOW_SCALING;
        float wy = ee[i].y + dt * fl[i].y;
        float wx = ee[i].z + dt * fl[i].x;
        float ty = floorf(wy), lx = floorf(wx);
        int ity = (int)ty, ixl = (int)lx;
        if (ity < -1 || ity > IWE_H - 1 || ixl < -1 || ixl > IWE_W - 1) continue; // no corner in image
        unsigned qy = min((unsigned)((wy - ty) * QMAX + 0.5f), 511u);
        unsigned qx = min((unsigned)((wx - lx) * QMAX + 0.5f), 511u);
        int band = ity >> 1; if (band < 0) band = 0;
        unsigned rr2 = (unsigned)(ity - band * 2 + 1);        // 0,1,2
        unsigned pol = (ee[i].w > 0.f) ? 1u : 0u;
        recw[i] = rr2 | ((unsigned)(ixl + 1) << 2) | (qy << 12) | (qx << 21) | (pol << 30);
        bands[i] = band;
        ranks[i] = atomicAdd(&s_cnt[band], 1u);
    }
    __syncthreads();
    for (int i = threadIdx.x; i < NBANDS; i += SCAT_BLOCK) {
        unsigned c = s_cnt[i];
        s_base[i] = c ? atomicAdd(&cursors[b * NBANDS + i], c) : 0u;
    }
    __syncthreads();
    #pragma unroll
    for (int i = 0; i < EV_PER_THREAD; ++i) {
        if (bands[i] < 0) continue;
        unsigned slot = s_base[bands[i]] + ranks[i];
        int bin = b * NBANDS + bands[i];
        if (slot < CAP) {
            recs[(size_t)bin * CAP + slot] = recw[i];
        } else {
            unsigned o = atomicAdd(ovf_cnt, 1u);
            if (o < OVF_CAP) ovf[o] = make_float2(__uint_as_float(recw[i]), (float)bin);
        }
    }
}

// ---------------- pass 2: per-band integer accumulation, native u64 LDS atomics ----
// tile entry e (e=0..BAND_H-1): lo32 = row y0g+e, hi32 = row y0g+e+1.
__global__ __launch_bounds__(512)
void band_splat(const unsigned* __restrict__ recs, const unsigned* __restrict__ cursors,
                float* __restrict__ out, float* __restrict__ halo)
{
    __shared__ unsigned long long tile[2 * BAND_H * IWE_W];   // 20.5 KB
    const int bg = blockIdx.x;
    const int band = bg % NBANDS;
    const int b = bg / NBANDS;
    const int y0g = band * BAND_H;

    for (int i = threadIdx.x; i < 2 * BAND_H * IWE_W; i += 512) tile[i] = 0ull;
    __syncthreads();

    unsigned cnt = cursors[bg]; if (cnt > CAP) cnt = CAP;
    const unsigned* r = recs + (size_t)bg * CAP;

    for (unsigned i = threadIdx.x; i < cnt; i += 512) {
        unsigned rec = r[i];
        unsigned rr2 = rec & 3u;
        int xi1      = (int)((rec >> 2) & 1023u);             // = xi+1 in [0,640]
        unsigned qy  = (rec >> 12) & 511u;
        unsigned qx  = (rec >> 21) & 511u;
        int plane    = (rec >> 30) & 1u ? 0 : 1;              // pos=plane0
        unsigned wy0 = 512u - qy, wy1 = qy;
        unsigned wx0 = 512u - qx, wx1 = qx;
        unsigned long long vL, vR;
        int entry;
        if (rr2 == 0u) {                                      // ity == -1: row 0 only
            entry = 0;
            vL = (unsigned long long)(wy1 * wx0);
            vR = (unsigned long long)(wy1 * wx1);
        } else {
            entry = (int)rr2 - 1;
            bool hiOK = (y0g + entry + 1) < IWE_H;            // mask halo past last row
            vL = (unsigned long long)(wy0 * wx0) |
                 ((unsigned long long)(hiOK ? wy1 * wx0 : 0u) << 32);
            vR = (unsigned long long)(wy0 * wx1) |
                 ((unsigned long long)(hiOK ? wy1 * wx1 : 0u) << 32);
        }
        unsigned long long* pl = tile + (plane * BAND_H + entry) * IWE_W;
        if (xi1 >= 1     && vL) atomicAdd(&pl[xi1 - 1], vL);
        if (xi1 <  IWE_W && vR) atomicAdd(&pl[xi1],     vR);
    }
    __syncthreads();

    for (int j = threadIdx.x; j < 2 * BAND_H * IWE_W; j += 512) {
        int plane = j / (BAND_H * IWE_W);
        int rem   = j % (BAND_H * IWE_W);
        int rr = rem / IWE_W, x = rem % IWE_W;
        unsigned v = (unsigned)(tile[(plane * BAND_H + rr) * IWE_W + x] & 0xffffffffu);
        if (rr > 0) v += (unsigned)(tile[(plane * BAND_H + rr - 1) * IWE_W + x] >> 32);
        out[(((size_t)b * 2 + plane) * IWE_H + (y0g + rr)) * IWE_W + x] =
            (float)v * (1.f / WSCALE);
    }
    for (int j = threadIdx.x; j < 2 * IWE_W; j += 512) {
        int plane = j / IWE_W, x = j % IWE_W;
        unsigned v = (unsigned)(tile[(plane * BAND_H + BAND_H - 1) * IWE_W + x] >> 32);
        halo[((size_t)bg * 2 + plane) * IWE_W + x] = (float)v * (1.f / WSCALE);
    }
}

// ---------------- pass 3: add halo rows (unique targets, no atomics) ----------------
__global__ void halo_add(const float* __restrict__ halo, float* __restrict__ out, int B)
{
    int t = blockIdx.x * blockDim.x + threadIdx.x;
    int total = B * (NBANDS - 1) * 2 * IWE_W;
    if (t >= total) return;
    int x = t % IWE_W; int rest = t / IWE_W;
    int plane = rest & 1; rest >>= 1;
    int bi = rest % (NBANDS - 1);
    int b  = rest / (NBANDS - 1);
    int bg = b * NBANDS + bi;
    float v = halo[((size_t)bg * 2 + plane) * IWE_W + x];
    size_t oi = (((size_t)b * 2 + plane) * IWE_H + (size_t)(bi + 1) * BAND_H) * IWE_W + x;
    out[oi] += v;
}

// ---------------- pass 4: overflow fallback (expected empty) ----------------
__global__ void ovf_splat(const float2* __restrict__ ovf, const unsigned* __restrict__ ovf_cnt,
                          float* __restrict__ out)
{
    unsigned cnt = *ovf_cnt; if (cnt > OVF_CAP) cnt = OVF_CAP;
    for (unsigned i = blockIdx.x * blockDim.x + threadIdx.x; i < cnt;
         i += gridDim.x * blockDim.x) {
        float2 e = ovf[i];
        unsigned rec = __float_as_uint(e.x);
        int bg = (int)e.y;
        int band = bg % NBANDS, b = bg / NBANDS;
        int y0g = band * BAND_H;
        unsigned rr2 = rec & 3u;
        int xi1      = (int)((rec >> 2) & 1023u);
        float fy = (float)((rec >> 12) & 511u) * (1.f / QMAX);
        float fx = (float)((rec >> 21) & 511u) * (1.f / QMAX);
        int plane    = (rec >> 30) & 1u ? 0 : 1;
        int ity = y0g + (int)rr2 - 1;
        float* pl = out + ((size_t)b * 2 + plane) * IWE_HW;
        bool xl = xi1 >= 1, xr = xi1 < IWE_W;
        if (ity >= 0) {                                   // ity in [0,479] by construction
            if (xl) atomicAdd(pl + ity * IWE_W + xi1 - 1, (1.f - fy) * (1.f - fx));
            if (xr) atomicAdd(pl + ity * IWE_W + xi1,     (1.f - fy) * fx);
        }
        if (ity + 1 < IWE_H) {
            if (xl) atomicAdd(pl + (ity + 1) * IWE_W + xi1 - 1, fy * (1.f - fx));
            if (xr) atomicAdd(pl + (ity + 1) * IWE_W + xi1,     fy * fx);
        }
    }
}

// ---------------- fallback: direct atomic splat ----------------
__global__ void iwe_direct_kernel(const float* __restrict__ ev, const float* __restrict__ flow,
                                  float* __restrict__ out, int N)
{
    int n = blockIdx.x * blockDim.x + threadIdx.x;
    int b = blockIdx.y;
    if (n >= N) return;
    float4 e = *reinterpret_cast<const float4*>(ev + ((size_t)b * N + n) * 4);
    float ts = e.x, y = e.y, x = e.z, p = e.w;
    const float* fb = flow + (size_t)b * 2 * IWE_HW;
    int lin0 = (int)(y * (float)IWE_W + x);
    float fx = fb[lin0], fy = fb[IWE_HW + lin0];
    float dt = (MAX_TS - ts) * FLOW_SCALING;
    float wy = y + dt * fy, wx = x + dt * fx;
    float ty = floorf(wy), lx = floorf(wx);
    float fyf = wy - ty, fxf = wx - lx;
    int iy = (int)ty, ix = (int)lx;
    float* plane = out + ((size_t)b * 2 + (p > 0.f ? 0 : 1)) * IWE_HW;
    if ((unsigned)iy < IWE_H) {
        if ((unsigned)ix       < IWE_W) atomicAdd(plane + iy * IWE_W + ix,     (1.f-fyf)*(1.f-fxf));
        if ((unsigned)(ix + 1) < IWE_W) atomicAdd(plane + iy * IWE_W + ix + 1, (1.f-fyf)*fxf);
    }
    if ((unsigned)(iy + 1) < IWE_H) {
        if ((unsigned)ix       < IWE_W) atomicAdd(plane + (iy+1) * IWE_W + ix,     fyf*(1.f-fxf));
        if ((unsigned)(ix + 1) < IWE_W) atomicAdd(plane + (iy+1) * IWE_W + ix + 1, fyf*fxf);
    }
}

extern "C" void kernel_launch(void* const* d_in, const int* in_sizes, int n_in,
                              void* d_out, int out_size, void* d_ws, size_t ws_size,
                              hipStream_t stream) {
    const float* ev   = (const float*)d_in[0];   // [B,N,4]
    const float* flow = (const float*)d_in[1];   // [B,2,H,W]
    float* out = (float*)d_out;                  // [B,2,H,W]

    int B = in_sizes[1] / (2 * IWE_HW);
    int N = in_sizes[0] / (4 * B);

    // workspace layout
    size_t off_cursors = 0;                                   // B*240 u32 (<=8KB)
    size_t off_ovfcnt  = 8192;
    size_t off_halo    = 12288;
    size_t halo_bytes  = (size_t)B * NBANDS * 2 * IWE_W * 4;
    size_t off_flowp   = (off_halo + halo_bytes + 255) & ~(size_t)255;
    size_t flowp_bytes = (size_t)B * IWE_HW * 8;
    size_t off_recs    = (off_flowp + flowp_bytes + 255) & ~(size_t)255;
    size_t recs_bytes  = (size_t)B * NBANDS * CAP * 4;        // u32 records
    size_t off_ovf     = off_recs + recs_bytes;
    size_t need        = off_ovf + (size_t)OVF_CAP * 8;

    if ((size_t)B * NBANDS * 4 > 8192 || need > ws_size) {
        hipMemsetAsync(d_out, 0, (size_t)out_size * sizeof(float), stream);
        dim3 grid((N + 255) / 256, B);
        iwe_direct_kernel<<<grid, dim3(256), 0, stream>>>(ev, flow, out, N);
        return;
    }

    char* ws = (char*)d_ws;
    unsigned* cursors = (unsigned*)(ws + off_cursors);
    unsigned* ovf_cnt = (unsigned*)(ws + off_ovfcnt);
    float*    halo    = (float*)(ws + off_halo);
    float2*   flowp   = (float2*)(ws + off_flowp);
    unsigned* recs    = (unsigned*)(ws + off_recs);
    float2*   ovf     = (float2*)(ws + off_ovf);

    int ftotal = B * IWE_HW;
    flow_pack<<<dim3((ftotal + 255) / 256), dim3(256), 0, stream>>>(
        flow, flowp, (unsigned*)d_ws, ftotal);

    int C = (N + CHUNK - 1) / CHUNK;
    if (B <= 8 && (8 % B) == 0) {
        int lpb = 8 / B;
        int iters = (C + lpb - 1) / lpb;
        ev_scatter<<<dim3(8 * iters), dim3(SCAT_BLOCK), 0, stream>>>(
            ev, flowp, recs, cursors, ovf_cnt, ovf, N, C, lpb);
    } else {
        ev_scatter<<<dim3(C, B), dim3(SCAT_BLOCK), 0, stream>>>(
            ev, flowp, recs, cursors, ovf_cnt, ovf, N, C, 0);
    }

    band_splat<<<dim3(B * NBANDS), dim3(512), 0, stream>>>(recs, cursors, out, halo);

    int htotal = B * (NBANDS - 1) * 2 * IWE_W;
    halo_add<<<dim3((htotal + 255) / 256), dim3(256), 0, stream>>>(halo, out, B);

    ovf_splat<<<dim3(64), dim3(256), 0, stream>>>(ovf, ovf_cnt, out);
}

// Round 8
// 66.997 us; speedup vs baseline: 2.9066x; 1.1035x over previous
//
#include <hip/hip_runtime.h>

#define IWE_H 480
#define IWE_W 640
#define IWE_HW (IWE_H * IWE_W)
#define FLOW_SCALING 128.0f
#define MAX_TS 1.0f

#define BAND_H 2
#define NBANDS (IWE_H / BAND_H)        // 240 bands of 2 rows
#define CAP 8192                       // slots per (batch,band); ~2x uniform mean 4167
#define OVF_CAP 262144
#define SCAT_BLOCK 256
#define EV_PER_THREAD 8
#define CHUNK (SCAT_BLOCK * EV_PER_THREAD)   // 2048 events per block
#define SCAN_N 256                     // scan width >= NBANDS
#define QMAX  512.0f
#define WSCALE (512.f * 512.f)         // weight fixed-point scale 2^18

static __device__ inline float4 nt_load4(const float4* p) {
    union { double d[2]; float4 v; } u;
    const double* q = (const double*)p;
    u.d[0] = __builtin_nontemporal_load(q);
    u.d[1] = __builtin_nontemporal_load(q + 1);
    return u.v;
}

// record (u32): [0:2) rr2  [2:12) xi+1  [12:21) qy  [21:30) qx  [30] pol
// rr2 = ity - 2*band + 1 in {0,1,2}; rr2==0 only for ity==-1 (band 0, row-0-only)

// ---------------- pass 0: pack flow to float2 + zero cursors/ovf_cnt ----------------
__global__ void flow_pack(const float* __restrict__ flow, float2* __restrict__ flowp,
                          unsigned* __restrict__ wszero, int total)
{
    int i = blockIdx.x * blockDim.x + threadIdx.x;
    if (i < 3072) wszero[i] = 0u;                         // cursors + ovf_cnt region
    if (i >= total) return;
    int b = i / IWE_HW, lin = i % IWE_HW;
    const float* fb = flow + (size_t)b * 2 * IWE_HW;
    flowp[i] = make_float2(fb[lin], fb[IWE_HW + lin]);    // (fx, fy)
}

// ---------------- pass 1: bin events into per-band u32 record buckets ----------------
__global__ __launch_bounds__(SCAT_BLOCK)
void ev_scatter(const float* __restrict__ ev, const float2* __restrict__ flowp,
                unsigned* __restrict__ recs, unsigned* __restrict__ cursors,
                unsigned* __restrict__ ovf_cnt, float2* __restrict__ ovf,
                int N, int C, int lpb)   // lpb = XCD lanes/batch (0 => 2D grid)
{
    __shared__ unsigned s_cnt[SCAN_N];
    __shared__ unsigned s_scan[SCAN_N];
    __shared__ unsigned s_base[NBANDS];
    __shared__ unsigned s_rec[CHUNK];
    __shared__ unsigned short s_band[CHUNK];

    int b, chunk;
    if (lpb) {                                    // XCD-pinned: blockIdx.x&7 ~ XCD
        int lane = blockIdx.x & 7;
        b = lane / lpb;
        chunk = ((int)(blockIdx.x >> 3)) * lpb + (lane % lpb);
    } else { b = blockIdx.y; chunk = blockIdx.x; }
    const int base_e = chunk * CHUNK;
    const bool live_chunk = (chunk < C);

    for (int i = threadIdx.x; i < SCAN_N; i += SCAT_BLOCK) s_cnt[i] = 0;
    __syncthreads();

    float4   ee[EV_PER_THREAD];
    float2   fl[EV_PER_THREAD];
    int      bands[EV_PER_THREAD];
    unsigned ranks[EV_PER_THREAD];
    unsigned recw[EV_PER_THREAD];

    const float2* fb = flowp + (size_t)b * IWE_HW;
    const float4* evb = reinterpret_cast<const float4*>(ev) + (size_t)b * N;

    // phase A: stream events (independent loads)
    #pragma unroll
    for (int i = 0; i < EV_PER_THREAD; ++i) {
        int e = base_e + i * SCAT_BLOCK + threadIdx.x;
        ee[i] = (live_chunk && e < N) ? nt_load4(evb + e)
                                      : make_float4(0.f, -1e9f, 0.f, 0.f);
    }
    // phase B: issue all flow gathers (8 in flight)
    #pragma unroll
    for (int i = 0; i < EV_PER_THREAD; ++i) {
        int lin0 = (int)(ee[i].y * (float)IWE_W + ee[i].z);   // exact: < 2^24
        fl[i] = (ee[i].y >= 0.f) ? fb[lin0] : make_float2(0.f, 0.f);
    }
    // phase C: warp, quantize, rank
    #pragma unroll
    for (int i = 0; i < EV_PER_THREAD; ++i) {
        bands[i] = -1;
        if (ee[i].y < 0.f) continue;
        float dt = (MAX_TS - ee[i].x) * FLOW_SCALING;
        float wy = ee[i].y + dt * fl[i].y;
        float wx = ee[i].z + dt * fl[i].x;
        float ty = floorf(wy), lx = floorf(wx);
        int ity = (int)ty, ixl = (int)lx;
        if (ity < -1 || ity > IWE_H - 1 || ixl < -1 || ixl > IWE_W - 1) continue; // no corner in image
        unsigned qy = min((unsigned)((wy - ty) * QMAX + 0.5f), 511u);
        unsigned qx = min((unsigned)((wx - lx) * QMAX + 0.5f), 511u);
        int band = ity >> 1; if (band < 0) band = 0;
        unsigned rr2 = (unsigned)(ity - band * 2 + 1);        // 0,1,2
        unsigned pol = (ee[i].w > 0.f) ? 1u : 0u;
        recw[i] = rr2 | ((unsigned)(ixl + 1) << 2) | (qy << 12) | (qx << 21) | (pol << 30);
        bands[i] = band;
        ranks[i] = atomicAdd(&s_cnt[band], 1u);
    }
    __syncthreads();

    // block-local inclusive prefix over bands (Hillis-Steele, SCAN_N wide)
    {
        int t = threadIdx.x;
        s_scan[t] = s_cnt[t];
        __syncthreads();                          // FIX: init visible before first read
        for (int off = 1; off < SCAN_N; off <<= 1) {
            unsigned u = (t >= off) ? s_scan[t - off] : 0u;
            __syncthreads();
            s_scan[t] += u;
            __syncthreads();
        }
        if (t < NBANDS) {
            unsigned c = s_cnt[t];
            s_base[t] = c ? atomicAdd(&cursors[b * NBANDS + t], c) : 0u;
        }
    }
    __syncthreads();

    // scatter records into LDS in band order
    #pragma unroll
    for (int i = 0; i < EV_PER_THREAD; ++i) {
        if (bands[i] < 0) continue;
        unsigned pos = s_scan[bands[i]] - s_cnt[bands[i]] + ranks[i];
        if (pos < CHUNK) {                        // defensive: never OOB LDS
            s_rec[pos]  = recw[i];
            s_band[pos] = (unsigned short)bands[i];
        }
    }
    __syncthreads();

    // coalesced global write: consecutive idx -> consecutive slots per band segment
    unsigned total = s_scan[SCAN_N - 1];
    if (total > CHUNK) total = CHUNK;             // defensive
    for (unsigned idx = threadIdx.x; idx < total; idx += SCAT_BLOCK) {
        unsigned band = s_band[idx];
        unsigned local = idx - (s_scan[band] - s_cnt[band]);
        unsigned slot = s_base[band] + local;
        int bin = b * NBANDS + (int)band;
        if (slot < CAP) {
            recs[(size_t)bin * CAP + slot] = s_rec[idx];
        } else {
            unsigned o = atomicAdd(ovf_cnt, 1u);
            if (o < OVF_CAP) ovf[o] = make_float2(__uint_as_float(s_rec[idx]), (float)bin);
        }
    }
}

// ---------------- pass 2: per-band integer accumulation, native u64 LDS atomics ----
// tile entry e (e=0..BAND_H-1): lo32 = row y0g+e, hi32 = row y0g+e+1.
__global__ __launch_bounds__(512)
void band_splat(const unsigned* __restrict__ recs, const unsigned* __restrict__ cursors,
                float* __restrict__ out, float* __restrict__ halo)
{
    __shared__ unsigned long long tile[2 * BAND_H * IWE_W];   // 20.5 KB
    const int bg = blockIdx.x;
    const int band = bg % NBANDS;
    const int b = bg / NBANDS;
    const int y0g = band * BAND_H;

    for (int i = threadIdx.x; i < 2 * BAND_H * IWE_W; i += 512) tile[i] = 0ull;
    __syncthreads();

    unsigned cnt = cursors[bg]; if (cnt > CAP) cnt = CAP;
    const unsigned* r = recs + (size_t)bg * CAP;

    for (unsigned i = threadIdx.x; i < cnt; i += 512) {
        unsigned rec = r[i];
        unsigned rr2 = rec & 3u;
        int xi1      = (int)((rec >> 2) & 1023u);             // = xi+1 in [0,640]
        unsigned qy  = (rec >> 12) & 511u;
        unsigned qx  = (rec >> 21) & 511u;
        int plane    = (rec >> 30) & 1u ? 0 : 1;              // pos=plane0
        unsigned wy0 = 512u - qy, wy1 = qy;
        unsigned wx0 = 512u - qx, wx1 = qx;
        unsigned long long vL, vR;
        int entry;
        if (rr2 == 0u) {                                      // ity == -1: row 0 only
            entry = 0;
            vL = (unsigned long long)(wy1 * wx0);
            vR = (unsigned long long)(wy1 * wx1);
        } else {
            entry = (int)rr2 - 1;
            bool hiOK = (y0g + entry + 1) < IWE_H;            // mask halo past last row
            vL = (unsigned long long)(wy0 * wx0) |
                 ((unsigned long long)(hiOK ? wy1 * wx0 : 0u) << 32);
            vR = (unsigned long long)(wy0 * wx1) |
                 ((unsigned long long)(hiOK ? wy1 * wx1 : 0u) << 32);
        }
        unsigned long long* pl = tile + (plane * BAND_H + entry) * IWE_W;
        if (xi1 >= 1     && vL) atomicAdd(&pl[xi1 - 1], vL);
        if (xi1 <  IWE_W && vR) atomicAdd(&pl[xi1],     vR);
    }
    __syncthreads();

    for (int j = threadIdx.x; j < 2 * BAND_H * IWE_W; j += 512) {
        int plane = j / (BAND_H * IWE_W);
        int rem   = j % (BAND_H * IWE_W);
        int rr = rem / IWE_W, x = rem % IWE_W;
        unsigned v = (unsigned)(tile[(plane * BAND_H + rr) * IWE_W + x] & 0xffffffffu);
        if (rr > 0) v += (unsigned)(tile[(plane * BAND_H + rr - 1) * IWE_W + x] >> 32);
        out[(((size_t)b * 2 + plane) * IWE_H + (y0g + rr)) * IWE_W + x] =
            (float)v * (1.f / WSCALE);
    }
    for (int j = threadIdx.x; j < 2 * IWE_W; j += 512) {
        int plane = j / IWE_W, x = j % IWE_W;
        unsigned v = (unsigned)(tile[(plane * BAND_H + BAND_H - 1) * IWE_W + x] >> 32);
        halo[((size_t)bg * 2 + plane) * IWE_W + x] = (float)v * (1.f / WSCALE);
    }
}

// ---------------- pass 3: add halo rows (unique targets, no atomics) ----------------
__global__ void halo_add(const float* __restrict__ halo, float* __restrict__ out, int B)
{
    int t = blockIdx.x * blockDim.x + threadIdx.x;
    int total = B * (NBANDS - 1) * 2 * IWE_W;
    if (t >= total) return;
    int x = t % IWE_W; int rest = t / IWE_W;
    int plane = rest & 1; rest >>= 1;
    int bi = rest % (NBANDS - 1);
    int b  = rest / (NBANDS - 1);
    int bg = b * NBANDS + bi;
    float v = halo[((size_t)bg * 2 + plane) * IWE_W + x];
    size_t oi = (((size_t)b * 2 + plane) * IWE_H + (size_t)(bi + 1) * BAND_H) * IWE_W + x;
    out[oi] += v;
}

// ---------------- pass 4: overflow fallback (expected empty) ----------------
__global__ void ovf_splat(const float2* __restrict__ ovf, const unsigned* __restrict__ ovf_cnt,
                          float* __restrict__ out)
{
    unsigned cnt = *ovf_cnt; if (cnt > OVF_CAP) cnt = OVF_CAP;
    for (unsigned i = blockIdx.x * blockDim.x + threadIdx.x; i < cnt;
         i += gridDim.x * blockDim.x) {
        float2 e = ovf[i];
        unsigned rec = __float_as_uint(e.x);
        int bg = (int)e.y;
        int band = bg % NBANDS, b = bg / NBANDS;
        int y0g = band * BAND_H;
        unsigned rr2 = rec & 3u;
        int xi1      = (int)((rec >> 2) & 1023u);
        float fy = (float)((rec >> 12) & 511u) * (1.f / QMAX);
        float fx = (float)((rec >> 21) & 511u) * (1.f / QMAX);
        int plane    = (rec >> 30) & 1u ? 0 : 1;
        int ity = y0g + (int)rr2 - 1;
        float* pl = out + ((size_t)b * 2 + plane) * IWE_HW;
        bool xl = xi1 >= 1, xr = xi1 < IWE_W;
        if (ity >= 0) {
            if (xl) atomicAdd(pl + ity * IWE_W + xi1 - 1, (1.f - fy) * (1.f - fx));
            if (xr) atomicAdd(pl + ity * IWE_W + xi1,     (1.f - fy) * fx);
        }
        if (ity + 1 < IWE_H) {
            if (xl) atomicAdd(pl + (ity + 1) * IWE_W + xi1 - 1, fy * (1.f - fx));
            if (xr) atomicAdd(pl + (ity + 1) * IWE_W + xi1,     fy * fx);
        }
    }
}

// ---------------- fallback: direct atomic splat ----------------
__global__ void iwe_direct_kernel(const float* __restrict__ ev, const float* __restrict__ flow,
                                  float* __restrict__ out, int N)
{
    int n = blockIdx.x * blockDim.x + threadIdx.x;
    int b = blockIdx.y;
    if (n >= N) return;
    float4 e = *reinterpret_cast<const float4*>(ev + ((size_t)b * N + n) * 4);
    float ts = e.x, y = e.y, x = e.z, p = e.w;
    const float* fb = flow + (size_t)b * 2 * IWE_HW;
    int lin0 = (int)(y * (float)IWE_W + x);
    float fx = fb[lin0], fy = fb[IWE_HW + lin0];
    float dt = (MAX_TS - ts) * FLOW_SCALING;
    float wy = y + dt * fy, wx = x + dt * fx;
    float ty = floorf(wy), lx = floorf(wx);
    float fyf = wy - ty, fxf = wx - lx;
    int iy = (int)ty, ix = (int)lx;
    float* plane = out + ((size_t)b * 2 + (p > 0.f ? 0 : 1)) * IWE_HW;
    if ((unsigned)iy < IWE_H) {
        if ((unsigned)ix       < IWE_W) atomicAdd(plane + iy * IWE_W + ix,     (1.f-fyf)*(1.f-fxf));
        if ((unsigned)(ix + 1) < IWE_W) atomicAdd(plane + iy * IWE_W + ix + 1, (1.f-fyf)*fxf);
    }
    if ((unsigned)(iy + 1) < IWE_H) {
        if ((unsigned)ix       < IWE_W) atomicAdd(plane + (iy+1) * IWE_W + ix,     fyf*(1.f-fxf));
        if ((unsigned)(ix + 1) < IWE_W) atomicAdd(plane + (iy+1) * IWE_W + ix + 1, fyf*fxf);
    }
}

extern "C" void kernel_launch(void* const* d_in, const int* in_sizes, int n_in,
                              void* d_out, int out_size, void* d_ws, size_t ws_size,
                              hipStream_t stream) {
    const float* ev   = (const float*)d_in[0];   // [B,N,4]
    const float* flow = (const float*)d_in[1];   // [B,2,H,W]
    float* out = (float*)d_out;                  // [B,2,H,W]

    int B = in_sizes[1] / (2 * IWE_HW);
    int N = in_sizes[0] / (4 * B);

    // workspace layout
    size_t off_cursors = 0;                                   // B*240 u32 (<=8KB)
    size_t off_ovfcnt  = 8192;
    size_t off_halo    = 12288;
    size_t halo_bytes  = (size_t)B * NBANDS * 2 * IWE_W * 4;
    size_t off_flowp   = (off_halo + halo_bytes + 255) & ~(size_t)255;
    size_t flowp_bytes = (size_t)B * IWE_HW * 8;
    size_t off_recs    = (off_flowp + flowp_bytes + 255) & ~(size_t)255;
    size_t recs_bytes  = (size_t)B * NBANDS * CAP * 4;        // u32 records
    size_t off_ovf     = off_recs + recs_bytes;
    size_t need        = off_ovf + (size_t)OVF_CAP * 8;

    if ((size_t)B * NBANDS * 4 > 8192 || need > ws_size) {
        hipMemsetAsync(d_out, 0, (size_t)out_size * sizeof(float), stream);
        dim3 grid((N + 255) / 256, B);
        iwe_direct_kernel<<<grid, dim3(256), 0, stream>>>(ev, flow, out, N);
        return;
    }

    char* ws = (char*)d_ws;
    unsigned* cursors = (unsigned*)(ws + off_cursors);
    unsigned* ovf_cnt = (unsigned*)(ws + off_ovfcnt);
    float*    halo    = (float*)(ws + off_halo);
    float2*   flowp   = (float2*)(ws + off_flowp);
    unsigned* recs    = (unsigned*)(ws + off_recs);
    float2*   ovf     = (float2*)(ws + off_ovf);

    int ftotal = B * IWE_HW;
    flow_pack<<<dim3((ftotal + 255) / 256), dim3(256), 0, stream>>>(
        flow, flowp, (unsigned*)d_ws, ftotal);

    int C = (N + CHUNK - 1) / CHUNK;
    if (B <= 8 && (8 % B) == 0) {
        int lpb = 8 / B;
        int iters = (C + lpb - 1) / lpb;
        ev_scatter<<<dim3(8 * iters), dim3(SCAT_BLOCK), 0, stream>>>(
            ev, flowp, recs, cursors, ovf_cnt, ovf, N, C, lpb);
    } else {
        ev_scatter<<<dim3(C, B), dim3(SCAT_BLOCK), 0, stream>>>(
            ev, flowp, recs, cursors, ovf_cnt, ovf, N, C, 0);
    }

    band_splat<<<dim3(B * NBANDS), dim3(512), 0, stream>>>(recs, cursors, out, halo);

    int htotal = B * (NBANDS - 1) * 2 * IWE_W;
    halo_add<<<dim3((htotal + 255) / 256), dim3(256), 0, stream>>>(halo, out, B);

    ovf_splat<<<dim3(64), dim3(256), 0, stream>>>(ovf, ovf_cnt, out);
}